// Round 1
// baseline (714.300 us; speedup 1.0000x reference)
//
#include <hip/hip_runtime.h>
#include <hip/hip_bf16.h>
#include <hip/hip_fp16.h>

// Problem constants
#define BB 1024
#define NN 60
#define FF 1024
#define NT 120  // 2*NN

// Output flat offsets (floats), in reference return order
#define OFF_X    0u          // (B,2,2048)
#define OFF_O1   4194304u    // (B,2,1024)
#define OFF_O2   6291456u
#define OFF_H1   8388608u    // (B,2,1024)
#define OFF_H2   10485760u
#define OFF_ATT1 12582912u   // (B,60)
#define OFF_ATT2 12644352u
#define OFF_A11  12705792u
#define OFF_A22  12767232u
#define OFF_A12  12828672u
#define OFF_A21  12890112u

typedef float f32x4 __attribute__((ext_vector_type(4)));
typedef _Float16 f16x8 __attribute__((ext_vector_type(8)));

// ---------------------------------------------------------------------------
// K1: per (batch, which_x): logits -> argmax over n -> write h row (fp32 copy)
// ---------------------------------------------------------------------------
__global__ __launch_bounds__(256) void k_select(const float* __restrict__ x1,
                                                const float* __restrict__ x2,
                                                const float* __restrict__ fc_w,
                                                float* __restrict__ out) {
  const int ba = blockIdx.x;       // b*2 + a
  const int b = ba >> 1, a = ba & 1;
  const float* xb = (a ? x2 : x1) + (size_t)b * NN * FF;
  const int tid = threadIdx.x, lane = tid & 63, wid = tid >> 6;

  __shared__ float lg[NN][2];
  __shared__ int idx_s[2];

  // hoist fc_w slices into registers (reused across 15 rows)
  float w0[16], w1[16];
#pragma unroll
  for (int t = 0; t < 16; ++t) {
    w0[t] = fc_w[t * 64 + lane];
    w1[t] = fc_w[FF + t * 64 + lane];
  }

  for (int i = 0; i < 15; ++i) {
    const int n = wid * 15 + i;
    const float* rp = xb + (size_t)n * FF;
    float a0 = 0.f, a1 = 0.f;
#pragma unroll
    for (int t = 0; t < 16; ++t) {
      const float v = rp[t * 64 + lane];
      a0 += v * w0[t];
      a1 += v * w1[t];
    }
    for (int off = 32; off; off >>= 1) {
      a0 += __shfl_xor(a0, off);
      a1 += __shfl_xor(a1, off);
    }
    if (lane == 0) { lg[n][0] = a0; lg[n][1] = a1; }
  }
  __syncthreads();

  if (wid == 0) {
    for (int c = 0; c < 2; ++c) {
      float v = (lane < NN) ? lg[lane][c] : -3e38f;
      int idx = lane;
      for (int off = 32; off; off >>= 1) {
        const float ov = __shfl_xor(v, off);
        const int oi = __shfl_xor(idx, off);
        if (ov > v || (ov == v && oi < idx)) { v = ov; idx = oi; }
      }
      if (lane == 0) idx_s[c] = idx;
    }
  }
  __syncthreads();

  float* hout = out + (a ? OFF_H2 : OFF_H1) + (size_t)b * 2 * FF;
  for (int c = 0; c < 2; ++c) {
    const float4* rp4 = (const float4*)(xb + (size_t)idx_s[c] * FF);
    float4* ho4 = (float4*)(hout + c * FF);
    ho4[tid] = rp4[tid];   // 256 threads * 16B = 4KB row
  }
}

// ---------------------------------------------------------------------------
// K1.5: convert tanh(h) and q_w to f16 in workspace
// ---------------------------------------------------------------------------
__global__ __launch_bounds__(256) void k_prep(const float* __restrict__ h,  // = out + OFF_H1 (h1||h2)
                                              const float* __restrict__ q_w,
                                              _Float16* __restrict__ Tb,
                                              _Float16* __restrict__ Wb) {
  const int T4 = 4096 * 1024 / 4;
  const int W4 = 1024 * 1024 / 4;
  const int stride = gridDim.x * blockDim.x;
  for (int i = blockIdx.x * blockDim.x + threadIdx.x; i < T4 + W4; i += stride) {
    if (i < T4) {
      const float4 v = ((const float4*)h)[i];
      union { _Float16 hh[4]; uint2 u; } pk;
      pk.hh[0] = (_Float16)tanhf(v.x);
      pk.hh[1] = (_Float16)tanhf(v.y);
      pk.hh[2] = (_Float16)tanhf(v.z);
      pk.hh[3] = (_Float16)tanhf(v.w);
      ((uint2*)Tb)[i] = pk.u;
    } else {
      const int j = i - T4;
      const float4 v = ((const float4*)q_w)[j];
      union { _Float16 hh[4]; uint2 u; } pk;
      pk.hh[0] = (_Float16)v.x;
      pk.hh[1] = (_Float16)v.y;
      pk.hh[2] = (_Float16)v.z;
      pk.hh[3] = (_Float16)v.w;
      ((uint2*)Wb)[j] = pk.u;
    }
  }
}

// ---------------------------------------------------------------------------
// K2: Qm[m,n] = sum_k Tb[m,k]*Wb[n,k] + q_b[n]   (M=4096, N=1024, K=1024)
// MFMA f16 16x16x32, 64x64 block tile, 4 waves each 32x32.
// ---------------------------------------------------------------------------
__global__ __launch_bounds__(256) void k_qm(const _Float16* __restrict__ Tb,
                                            const _Float16* __restrict__ Wb,
                                            const float* __restrict__ q_b,
                                            float* __restrict__ Qm) {
  const int m0 = blockIdx.x * 64;
  const int n0 = blockIdx.y * 64;
  const int tid = threadIdx.x, lane = tid & 63, wid = tid >> 6;
  const int wm = wid & 1, wn = wid >> 1;

  __shared__ _Float16 As[64][32];
  __shared__ _Float16 Bs[64][32];

  f32x4 acc[2][2] = {};

  const int lrow = tid >> 2;        // 0..63
  const int lcol = (tid & 3) * 8;   // 0,8,16,24
  const int ms = wm * 32 + (lane & 15);
  const int ns = wn * 32 + (lane & 15);
  const int ks = (lane >> 4) * 8;

  for (int k0 = 0; k0 < 1024; k0 += 32) {
    __syncthreads();
    *(uint4*)(&As[lrow][lcol]) = *(const uint4*)(Tb + (size_t)(m0 + lrow) * 1024 + k0 + lcol);
    *(uint4*)(&Bs[lrow][lcol]) = *(const uint4*)(Wb + (size_t)(n0 + lrow) * 1024 + k0 + lcol);
    __syncthreads();
#pragma unroll
    for (int mi = 0; mi < 2; ++mi) {
      const f16x8 af = *(const f16x8*)(&As[ms + mi * 16][ks]);
#pragma unroll
      for (int ni = 0; ni < 2; ++ni) {
        const f16x8 bf = *(const f16x8*)(&Bs[ns + ni * 16][ks]);
        acc[mi][ni] = __builtin_amdgcn_mfma_f32_16x16x32_f16(af, bf, acc[mi][ni], 0, 0, 0);
      }
    }
  }

  const int col = lane & 15, quad = lane >> 4;
#pragma unroll
  for (int mi = 0; mi < 2; ++mi) {
#pragma unroll
    for (int ni = 0; ni < 2; ++ni) {
      const int n = n0 + wn * 32 + ni * 16 + col;
      const float qb = q_b[n];
#pragma unroll
      for (int r = 0; r < 4; ++r) {
        const int m = m0 + wm * 32 + mi * 16 + quad * 4 + r;
        Qm[(size_t)m * 1024 + n] = acc[mi][ni][r] + qb;
      }
    }
  }
}

// ---------------------------------------------------------------------------
// K3: per batch: scores -> softmax (+small outputs) -> out = 0.9*A^T L + 0.1*qm
// ---------------------------------------------------------------------------
__global__ __launch_bounds__(256) void k_attend(const float* __restrict__ x1,
                                                const float* __restrict__ x2,
                                                const float* __restrict__ Qm,
                                                float* __restrict__ out) {
  const int b = blockIdx.x;
  const int tid = threadIdx.x, lane = tid & 63, wid = tid >> 6;

  __shared__ float qm_l[4][FF];   // j = a*2 + c
  __shared__ float s_l[4][128];   // scores then normalized A

  // phase 0: load qm rows
#pragma unroll
  for (int j = 0; j < 4; ++j) {
    const int r = (j >> 1) * 2048 + b * 2 + (j & 1);
    ((float4*)qm_l[j])[tid] = ((const float4*)(Qm + (size_t)r * FF))[tid];
  }
  __syncthreads();

  const float* xb1 = x1 + (size_t)b * NN * FF;
  const float* xb2 = x2 + (size_t)b * NN * FF;

  // hoist this lane's qm strides into registers
  float qr[4][16];
#pragma unroll
  for (int j = 0; j < 4; ++j)
#pragma unroll
    for (int t = 0; t < 16; ++t) qr[j][t] = qm_l[j][t * 64 + lane];

  // phase 1: scores s[j][n] = (L[n,:] . qm[j,:]) / 32
  for (int i = 0; i < 30; ++i) {
    const int n = wid * 30 + i;
    const float* rp = (n < NN) ? (xb1 + (size_t)n * FF) : (xb2 + (size_t)(n - NN) * FF);
    float a0 = 0.f, a1 = 0.f, a2 = 0.f, a3 = 0.f;
#pragma unroll
    for (int t = 0; t < 16; ++t) {
      const float v = rp[t * 64 + lane];
      a0 += v * qr[0][t];
      a1 += v * qr[1][t];
      a2 += v * qr[2][t];
      a3 += v * qr[3][t];
    }
    for (int off = 32; off; off >>= 1) {
      a0 += __shfl_xor(a0, off);
      a1 += __shfl_xor(a1, off);
      a2 += __shfl_xor(a2, off);
      a3 += __shfl_xor(a3, off);
    }
    if (lane == 0) {
      s_l[0][n] = a0 * 0.03125f;
      s_l[1][n] = a1 * 0.03125f;
      s_l[2][n] = a2 * 0.03125f;
      s_l[3][n] = a3 * 0.03125f;
    }
  }
  __syncthreads();

  // phase 2: softmax over n (120) per j; wave wid handles j=wid; write small outs
  {
    const int j = wid;
    const bool has1 = (lane + 64) < NT;
    const float v0 = s_l[j][lane];
    const float v1 = has1 ? s_l[j][lane + 64] : -3e38f;
    float m = fmaxf(v0, v1);
    for (int off = 32; off; off >>= 1) m = fmaxf(m, __shfl_xor(m, off));
    const float e0 = expf(v0 - m);
    const float e1 = has1 ? expf(v1 - m) : 0.f;
    float d = e0 + e1;
    for (int off = 32; off; off >>= 1) d += __shfl_xor(d, off);
    const float inv = 1.f / d;
    const float p0 = e0 * inv, p1 = e1 * inv;
    s_l[j][lane] = p0;
    if (has1) s_l[j][lane + 64] = p1;

    const int nb = b * NN;
    if (j == 0) {                       // A1, c=0 -> ATT1 = A1[:, :60, 0]
      if (lane < NN) out[OFF_ATT1 + nb + lane] = p0;
    } else if (j == 1) {                // A1, c=1 -> att11 (n<60), att12 (n>=60)
      if (lane < NN) out[OFF_A11 + nb + lane] = p0;
      if (lane >= NN) out[OFF_A12 + nb + (lane - NN)] = p0;
      if (has1) out[OFF_A12 + nb + (lane + 4)] = p1;
    } else if (j == 2) {                // A2, c=0 -> ATT2 = A2[:, 60:, 0]
      if (lane >= NN) out[OFF_ATT2 + nb + (lane - NN)] = p0;
      if (has1) out[OFF_ATT2 + nb + (lane + 4)] = p1;
    } else {                            // A2, c=1 -> att22 (n>=60), att21 (n<60)
      if (lane >= NN) out[OFF_A22 + nb + (lane - NN)] = p0;
      if (has1) out[OFF_A22 + nb + (lane + 4)] = p1;
      if (lane < NN) out[OFF_A21 + nb + lane] = p0;
    }
  }
  __syncthreads();

  // phase 3: out[j][f] = 0.9 * sum_n A[j][n] * L[n][f] + 0.1 * qm[j][f]
  {
    float acc[4][4] = {};
    const int f = tid * 4;
    for (int n = 0; n < NT; ++n) {
      const float* rp = (n < NN) ? (xb1 + (size_t)n * FF) : (xb2 + (size_t)(n - NN) * FF);
      const float4 v = *(const float4*)(rp + f);
      const float ve0 = v.x, ve1 = v.y, ve2 = v.z, ve3 = v.w;
#pragma unroll
      for (int j = 0; j < 4; ++j) {
        const float w = s_l[j][n];
        acc[j][0] += w * ve0;
        acc[j][1] += w * ve1;
        acc[j][2] += w * ve2;
        acc[j][3] += w * ve3;
      }
    }
#pragma unroll
    for (int j = 0; j < 4; ++j) {
      const int aa = j >> 1, c = j & 1;
      float4 r;
      r.x = 0.9f * acc[j][0] + 0.1f * qm_l[j][f + 0];
      r.y = 0.9f * acc[j][1] + 0.1f * qm_l[j][f + 1];
      r.z = 0.9f * acc[j][2] + 0.1f * qm_l[j][f + 2];
      r.w = 0.9f * acc[j][3] + 0.1f * qm_l[j][f + 3];
      float* o = out + (aa ? OFF_O2 : OFF_O1) + ((size_t)b * 2 + c) * FF + f;
      *(float4*)o = r;
      float* xo = out + OFF_X + ((size_t)b * 2 + c) * 2048 + aa * FF + f;
      *(float4*)xo = r;
    }
  }
}

// ---------------------------------------------------------------------------
extern "C" void kernel_launch(void* const* d_in, const int* in_sizes, int n_in,
                              void* d_out, int out_size, void* d_ws, size_t ws_size,
                              hipStream_t stream) {
  const float* x1 = (const float*)d_in[0];
  const float* x2 = (const float*)d_in[1];
  const float* fc_w = (const float*)d_in[2];
  // d_in[3] = fc_b: constant per class, does not change the argmax -> unused
  const float* q_w = (const float*)d_in[4];
  const float* q_b = (const float*)d_in[5];
  float* out = (float*)d_out;

  // workspace: Tb (4096x1024 f16, 8MB) | Wb (1024x1024 f16, 2MB) | Qm (4096x1024 f32, 16MB)
  _Float16* Tb = (_Float16*)d_ws;
  _Float16* Wb = Tb + 4096 * 1024;
  float* Qm = (float*)(Wb + 1024 * 1024);

  k_select<<<2 * BB, 256, 0, stream>>>(x1, x2, fc_w, out);
  k_prep<<<2048, 256, 0, stream>>>(out + OFF_H1, q_w, Tb, Wb);
  k_qm<<<dim3(64, 16), 256, 0, stream>>>(Tb, Wb, q_b, Qm);
  k_attend<<<BB, 256, 0, stream>>>(x1, x2, Qm, out);
}

// Round 2
// 705.319 us; speedup vs baseline: 1.0127x; 1.0127x over previous
//
#include <hip/hip_runtime.h>
#include <hip/hip_bf16.h>
#include <hip/hip_fp16.h>

// Problem constants
#define BB 1024
#define NN 60
#define FF 1024
#define NT 120  // 2*NN

// Output flat offsets (floats), in reference return order
#define OFF_X    0u          // (B,2,2048)
#define OFF_O1   4194304u    // (B,2,1024)
#define OFF_O2   6291456u
#define OFF_H1   8388608u    // (B,2,1024)
#define OFF_H2   10485760u
#define OFF_ATT1 12582912u   // (B,60)
#define OFF_ATT2 12644352u
#define OFF_A11  12705792u
#define OFF_A22  12767232u
#define OFF_A12  12828672u
#define OFF_A21  12890112u

typedef float f32x4 __attribute__((ext_vector_type(4)));
typedef _Float16 f16x8 __attribute__((ext_vector_type(8)));

__device__ __forceinline__ float dot4(const float4 a, const float4 b) {
  return a.x * b.x + a.y * b.y + a.z * b.z + a.w * b.w;
}

// ---------------------------------------------------------------------------
// K1: per (batch, which_x): logits -> argmax over n -> write h row (fp32) and
// tanh(h) as f16 into Tb (fused; kills k_prep's 32MB h re-read).
// ---------------------------------------------------------------------------
__global__ __launch_bounds__(256) void k_select(const float* __restrict__ x1,
                                                const float* __restrict__ x2,
                                                const float* __restrict__ fc_w,
                                                float* __restrict__ out,
                                                _Float16* __restrict__ Tb) {
  const int ba = blockIdx.x;       // b*2 + a
  const int b = ba >> 1, a = ba & 1;
  const float* xb = (a ? x2 : x1) + (size_t)b * NN * FF;
  const int tid = threadIdx.x, lane = tid & 63, wid = tid >> 6;

  __shared__ float lg[NN][2];
  __shared__ int idx_s[2];

  // fc_w slices in float4 registers (reused across 15 rows)
  float4 w0[4], w1[4];
#pragma unroll
  for (int t = 0; t < 4; ++t) {
    w0[t] = *(const float4*)(fc_w + t * 256 + lane * 4);
    w1[t] = *(const float4*)(fc_w + FF + t * 256 + lane * 4);
  }

  for (int i = 0; i < 15; ++i) {
    const int n = wid * 15 + i;
    const float* rp = xb + (size_t)n * FF;
    float4 v[4];
#pragma unroll
    for (int t = 0; t < 4; ++t) v[t] = *(const float4*)(rp + t * 256 + lane * 4);
    float a0 = 0.f, a1 = 0.f;
#pragma unroll
    for (int t = 0; t < 4; ++t) {
      a0 += dot4(v[t], w0[t]);
      a1 += dot4(v[t], w1[t]);
    }
    for (int off = 32; off; off >>= 1) {
      a0 += __shfl_xor(a0, off);
      a1 += __shfl_xor(a1, off);
    }
    if (lane == 0) { lg[n][0] = a0; lg[n][1] = a1; }
  }
  __syncthreads();

  if (wid == 0) {
    for (int c = 0; c < 2; ++c) {
      float v = (lane < NN) ? lg[lane][c] : -3e38f;
      int idx = lane;
      for (int off = 32; off; off >>= 1) {
        const float ov = __shfl_xor(v, off);
        const int oi = __shfl_xor(idx, off);
        if (ov > v || (ov == v && oi < idx)) { v = ov; idx = oi; }
      }
      if (lane == 0) idx_s[c] = idx;
    }
  }
  __syncthreads();

  float* hout = out + (a ? OFF_H2 : OFF_H1) + (size_t)b * 2 * FF;
  _Float16* tout = Tb + ((size_t)a * 2048 + (size_t)b * 2) * FF;
  for (int c = 0; c < 2; ++c) {
    const float4 v = ((const float4*)(xb + (size_t)idx_s[c] * FF))[tid];
    ((float4*)(hout + c * FF))[tid] = v;
    union { _Float16 hh[4]; uint2 u; } pk;
    pk.hh[0] = (_Float16)tanhf(v.x);
    pk.hh[1] = (_Float16)tanhf(v.y);
    pk.hh[2] = (_Float16)tanhf(v.z);
    pk.hh[3] = (_Float16)tanhf(v.w);
    ((uint2*)(tout + c * FF))[tid] = pk.u;
  }
}

// ---------------------------------------------------------------------------
// K1.5: convert q_w to f16 (4MB read, trivial)
// ---------------------------------------------------------------------------
__global__ __launch_bounds__(256) void k_prepw(const float* __restrict__ q_w,
                                               _Float16* __restrict__ Wb) {
  const int i = blockIdx.x * 256 + threadIdx.x;   // 262144 float4s
  const float4 v = ((const float4*)q_w)[i];
  union { _Float16 hh[4]; uint2 u; } pk;
  pk.hh[0] = (_Float16)v.x;
  pk.hh[1] = (_Float16)v.y;
  pk.hh[2] = (_Float16)v.z;
  pk.hh[3] = (_Float16)v.w;
  ((uint2*)Wb)[i] = pk.u;
}

// ---------------------------------------------------------------------------
// K2: Qm[m,n] = sum_k Tb[m,k]*Wb[n,k] + q_b[n]   (M=4096, N=1024, K=1024)
// MFMA f16 16x16x32; 128x128 block tile, 4 waves each 64x64 (4x4 frags).
// LDS rows padded to 40 halfs (80B): 16B-aligned, 2-way-only banking (free).
// ---------------------------------------------------------------------------
__global__ __launch_bounds__(256) void k_qm(const _Float16* __restrict__ Tb,
                                            const _Float16* __restrict__ Wb,
                                            const float* __restrict__ q_b,
                                            float* __restrict__ Qm) {
  const int m0 = blockIdx.x * 128;
  const int n0 = blockIdx.y * 128;
  const int tid = threadIdx.x, lane = tid & 63, wid = tid >> 6;
  const int wm = wid & 1, wn = wid >> 1;

  __shared__ _Float16 As[128][40];
  __shared__ _Float16 Bs[128][40];

  f32x4 acc[4][4] = {};

  const int srow = tid >> 1;          // 0..127
  const int scol = (tid & 1) * 16;    // 0 or 16
  const int fr = lane & 15;
  const int ks = (lane >> 4) * 8;

  const _Float16* Ag = Tb + (size_t)(m0 + srow) * 1024 + scol;
  const _Float16* Bg = Wb + (size_t)(n0 + srow) * 1024 + scol;

  for (int k0 = 0; k0 < 1024; k0 += 32) {
    __syncthreads();
    *(uint4*)(&As[srow][scol])     = *(const uint4*)(Ag + k0);
    *(uint4*)(&As[srow][scol + 8]) = *(const uint4*)(Ag + k0 + 8);
    *(uint4*)(&Bs[srow][scol])     = *(const uint4*)(Bg + k0);
    *(uint4*)(&Bs[srow][scol + 8]) = *(const uint4*)(Bg + k0 + 8);
    __syncthreads();

    f16x8 af[4], bf[4];
#pragma unroll
    for (int mi = 0; mi < 4; ++mi) af[mi] = *(const f16x8*)(&As[wm * 64 + mi * 16 + fr][ks]);
#pragma unroll
    for (int ni = 0; ni < 4; ++ni) bf[ni] = *(const f16x8*)(&Bs[wn * 64 + ni * 16 + fr][ks]);
#pragma unroll
    for (int mi = 0; mi < 4; ++mi)
#pragma unroll
      for (int ni = 0; ni < 4; ++ni)
        acc[mi][ni] = __builtin_amdgcn_mfma_f32_16x16x32_f16(af[mi], bf[ni], acc[mi][ni], 0, 0, 0);
  }

  const int col = lane & 15, quad = lane >> 4;
#pragma unroll
  for (int ni = 0; ni < 4; ++ni) {
    const int n = n0 + wn * 64 + ni * 16 + col;
    const float qb = q_b[n];
#pragma unroll
    for (int mi = 0; mi < 4; ++mi) {
#pragma unroll
      for (int r = 0; r < 4; ++r) {
        const int m = m0 + wm * 64 + mi * 16 + quad * 4 + r;
        Qm[(size_t)m * 1024 + n] = acc[mi][ni][r] + qb;
      }
    }
  }
}

// ---------------------------------------------------------------------------
// K3: per batch: scores -> softmax (+small outputs) -> out = 0.9*A^T L + 0.1*qm
// ---------------------------------------------------------------------------
__global__ __launch_bounds__(256) void k_attend(const float* __restrict__ x1,
                                                const float* __restrict__ x2,
                                                const float* __restrict__ Qm,
                                                float* __restrict__ out) {
  const int b = blockIdx.x;
  const int tid = threadIdx.x, lane = tid & 63, wid = tid >> 6;

  __shared__ float qm_l[4][FF];   // j = a*2 + c
  __shared__ float s_l[4][128];   // raw scores
  __shared__ float s_t[128][4];   // normalized A, transposed for phase 3

  // phase 0: load qm rows
#pragma unroll
  for (int j = 0; j < 4; ++j) {
    const int r = (j >> 1) * 2048 + b * 2 + (j & 1);
    ((float4*)qm_l[j])[tid] = ((const float4*)(Qm + (size_t)r * FF))[tid];
  }
  __syncthreads();

  const float* xb1 = x1 + (size_t)b * NN * FF;
  const float* xb2 = x2 + (size_t)b * NN * FF;

  // hoist this lane's qm slices into float4 registers
  float4 qr[4][4];
#pragma unroll
  for (int j = 0; j < 4; ++j)
#pragma unroll
    for (int t = 0; t < 4; ++t) qr[j][t] = *(const float4*)(&qm_l[j][t * 256 + lane * 4]);

  // phase 1: scores s[j][n] = (L[n,:] . qm[j,:]) / 32 — 2 rows per iter
  for (int i = 0; i < 30; i += 2) {
    const int n0 = wid * 30 + i, n1 = n0 + 1;
    const float* rp0 = (n0 < NN) ? (xb1 + (size_t)n0 * FF) : (xb2 + (size_t)(n0 - NN) * FF);
    const float* rp1 = (n1 < NN) ? (xb1 + (size_t)n1 * FF) : (xb2 + (size_t)(n1 - NN) * FF);
    float4 u[4], v[4];
#pragma unroll
    for (int t = 0; t < 4; ++t) {
      u[t] = *(const float4*)(rp0 + t * 256 + lane * 4);
      v[t] = *(const float4*)(rp1 + t * 256 + lane * 4);
    }
    float acc0[4] = {0.f, 0.f, 0.f, 0.f}, acc1[4] = {0.f, 0.f, 0.f, 0.f};
#pragma unroll
    for (int t = 0; t < 4; ++t) {
#pragma unroll
      for (int j = 0; j < 4; ++j) {
        acc0[j] += dot4(u[t], qr[j][t]);
        acc1[j] += dot4(v[t], qr[j][t]);
      }
    }
    for (int off = 32; off; off >>= 1) {
#pragma unroll
      for (int j = 0; j < 4; ++j) {
        acc0[j] += __shfl_xor(acc0[j], off);
        acc1[j] += __shfl_xor(acc1[j], off);
      }
    }
    if (lane == 0) {
#pragma unroll
      for (int j = 0; j < 4; ++j) {
        s_l[j][n0] = acc0[j] * 0.03125f;
        s_l[j][n1] = acc1[j] * 0.03125f;
      }
    }
  }
  __syncthreads();

  // phase 2: softmax over n (120) per j; wave wid handles j=wid; write small outs
  {
    const int j = wid;
    const bool has1 = (lane + 64) < NT;
    const float v0 = s_l[j][lane];
    const float v1 = has1 ? s_l[j][lane + 64] : -3e38f;
    float m = fmaxf(v0, v1);
    for (int off = 32; off; off >>= 1) m = fmaxf(m, __shfl_xor(m, off));
    const float e0 = expf(v0 - m);
    const float e1 = has1 ? expf(v1 - m) : 0.f;
    float d = e0 + e1;
    for (int off = 32; off; off >>= 1) d += __shfl_xor(d, off);
    const float inv = 1.f / d;
    const float p0 = e0 * inv, p1 = e1 * inv;
    s_t[lane][j] = p0;
    if (has1) s_t[lane + 64][j] = p1;

    const int nb = b * NN;
    if (j == 0) {                       // A1, c=0 -> ATT1 = A1[:, :60, 0]
      if (lane < NN) out[OFF_ATT1 + nb + lane] = p0;
    } else if (j == 1) {                // A1, c=1 -> att11 (n<60), att12 (n>=60)
      if (lane < NN) out[OFF_A11 + nb + lane] = p0;
      if (lane >= NN) out[OFF_A12 + nb + (lane - NN)] = p0;
      if (has1) out[OFF_A12 + nb + (lane + 4)] = p1;
    } else if (j == 2) {                // A2, c=0 -> ATT2 = A2[:, 60:, 0]
      if (lane >= NN) out[OFF_ATT2 + nb + (lane - NN)] = p0;
      if (has1) out[OFF_ATT2 + nb + (lane + 4)] = p1;
    } else {                            // A2, c=1 -> att22 (n>=60), att21 (n<60)
      if (lane >= NN) out[OFF_A22 + nb + (lane - NN)] = p0;
      if (has1) out[OFF_A22 + nb + (lane + 4)] = p1;
      if (lane < NN) out[OFF_A21 + nb + lane] = p0;
    }
  }
  __syncthreads();

  // phase 3: out[j][f] = 0.9 * sum_n A[j][n] * L[n][f] + 0.1 * qm[j][f]
  {
    float acc[4][4] = {};
    const int f = tid * 4;
    for (int n = 0; n < NT; n += 2) {
      const float* rp0 = (n < NN) ? (xb1 + (size_t)n * FF) : (xb2 + (size_t)(n - NN) * FF);
      const float* rp1 = (n + 1 < NN) ? (xb1 + (size_t)(n + 1) * FF) : (xb2 + (size_t)(n + 1 - NN) * FF);
      const float4 v0 = *(const float4*)(rp0 + f);
      const float4 v1 = *(const float4*)(rp1 + f);
      const float4 A0 = *(const float4*)(&s_t[n][0]);       // broadcast ds_read_b128
      const float4 A1 = *(const float4*)(&s_t[n + 1][0]);
      const float w00 = A0.x, w01 = A0.y, w02 = A0.z, w03 = A0.w;
      const float w10 = A1.x, w11 = A1.y, w12 = A1.z, w13 = A1.w;
      acc[0][0] += w00 * v0.x + w10 * v1.x;
      acc[0][1] += w00 * v0.y + w10 * v1.y;
      acc[0][2] += w00 * v0.z + w10 * v1.z;
      acc[0][3] += w00 * v0.w + w10 * v1.w;
      acc[1][0] += w01 * v0.x + w11 * v1.x;
      acc[1][1] += w01 * v0.y + w11 * v1.y;
      acc[1][2] += w01 * v0.z + w11 * v1.z;
      acc[1][3] += w01 * v0.w + w11 * v1.w;
      acc[2][0] += w02 * v0.x + w12 * v1.x;
      acc[2][1] += w02 * v0.y + w12 * v1.y;
      acc[2][2] += w02 * v0.z + w12 * v1.z;
      acc[2][3] += w02 * v0.w + w12 * v1.w;
      acc[3][0] += w03 * v0.x + w13 * v1.x;
      acc[3][1] += w03 * v0.y + w13 * v1.y;
      acc[3][2] += w03 * v0.z + w13 * v1.z;
      acc[3][3] += w03 * v0.w + w13 * v1.w;
    }
#pragma unroll
    for (int j = 0; j < 4; ++j) {
      const int aa = j >> 1, c = j & 1;
      float4 r;
      r.x = 0.9f * acc[j][0] + 0.1f * qm_l[j][f + 0];
      r.y = 0.9f * acc[j][1] + 0.1f * qm_l[j][f + 1];
      r.z = 0.9f * acc[j][2] + 0.1f * qm_l[j][f + 2];
      r.w = 0.9f * acc[j][3] + 0.1f * qm_l[j][f + 3];
      float* o = out + (aa ? OFF_O2 : OFF_O1) + ((size_t)b * 2 + c) * FF + f;
      *(float4*)o = r;
      float* xo = out + OFF_X + ((size_t)b * 2 + c) * 2048 + aa * FF + f;
      *(float4*)xo = r;
    }
  }
}

// ---------------------------------------------------------------------------
extern "C" void kernel_launch(void* const* d_in, const int* in_sizes, int n_in,
                              void* d_out, int out_size, void* d_ws, size_t ws_size,
                              hipStream_t stream) {
  const float* x1 = (const float*)d_in[0];
  const float* x2 = (const float*)d_in[1];
  const float* fc_w = (const float*)d_in[2];
  // d_in[3] = fc_b: constant per class, does not change the argmax -> unused
  const float* q_w = (const float*)d_in[4];
  const float* q_b = (const float*)d_in[5];
  float* out = (float*)d_out;

  // workspace: Tb (4096x1024 f16, 8MB) | Wb (1024x1024 f16, 2MB) | Qm (4096x1024 f32, 16MB)
  _Float16* Tb = (_Float16*)d_ws;
  _Float16* Wb = Tb + 4096 * 1024;
  float* Qm = (float*)(Wb + 1024 * 1024);

  k_select<<<2 * BB, 256, 0, stream>>>(x1, x2, fc_w, out, Tb);
  k_prepw<<<1024, 256, 0, stream>>>(q_w, Wb);
  k_qm<<<dim3(32, 8), 256, 0, stream>>>(Tb, Wb, q_b, Qm);
  k_attend<<<BB, 256, 0, stream>>>(x1, x2, Qm, out);
}